// Round 1
// baseline (2672.673 us; speedup 1.0000x reference)
//
#include <hip/hip_runtime.h>
#include <hip/hip_bf16.h>

// ---------------------------------------------------------------------------
// VoxelBackBone8x: 12 sparse 3D conv layers, each followed by global BN+ReLU.
// Strategy: dense int32 index grids per level (coord -> row), direct gather
// conv (thread = (out_point, cout)), block-reduce for BN stats, elementwise
// BN+ReLU apply. All fp32.
// ---------------------------------------------------------------------------

__global__ __launch_bounds__(256) void scatter_grid(const int* __restrict__ coords, int n,
                                                    int* __restrict__ grid, int D, int H, int W) {
    int i = blockIdx.x * blockDim.x + threadIdx.x;
    if (i >= n) return;
    const int b = coords[4*i+0], z = coords[4*i+1], y = coords[4*i+2], x = coords[4*i+3];
    grid[(((size_t)b*D + z)*H + y)*W + x] = i;
}

template<int CIN, int COUT, int KD, int KH, int KW>
__global__ __launch_bounds__(256) void sp_conv(
    const float* __restrict__ fin, const int* __restrict__ grid,
    const int* __restrict__ oc, int n_out,
    const float* __restrict__ w, float* __restrict__ out,
    int D, int H, int W, int sz, int sy, int sx, int pz, int py, int px)
{
    constexpr int PTS = 256 / COUT;
    const int c = threadIdx.x % COUT;
    const int p = blockIdx.x * PTS + threadIdx.x / COUT;
    if (p >= n_out) return;
    const int b   = oc[4*p+0];
    const int iz0 = oc[4*p+1]*sz - pz;
    const int iy0 = oc[4*p+2]*sy - py;
    const int ix0 = oc[4*p+3]*sx - px;
    const int* gb = grid + (size_t)b * D * H * W;
    float acc = 0.f;
    for (int kd = 0; kd < KD; ++kd) {
        const int iz = iz0 + kd;
        if ((unsigned)iz >= (unsigned)D) continue;
        for (int kh = 0; kh < KH; ++kh) {
            const int iy = iy0 + kh;
            if ((unsigned)iy >= (unsigned)H) continue;
            for (int kw = 0; kw < KW; ++kw) {
                const int ix = ix0 + kw;
                if ((unsigned)ix >= (unsigned)W) continue;
                const int idx = gb[((size_t)iz*H + iy)*W + ix];
                if (idx < 0) continue;
                const float4* f4 = reinterpret_cast<const float4*>(fin + (size_t)idx * CIN);
                const float* wp  = w + ((size_t)((kd*KH + kh)*KW + kw) * CIN) * COUT + c;
#pragma unroll
                for (int q = 0; q < CIN/4; ++q) {
                    const float4 v = f4[q];
                    acc = fmaf(v.x, wp[(4*q+0)*COUT], acc);
                    acc = fmaf(v.y, wp[(4*q+1)*COUT], acc);
                    acc = fmaf(v.z, wp[(4*q+2)*COUT], acc);
                    acc = fmaf(v.w, wp[(4*q+3)*COUT], acc);
                }
            }
        }
    }
    out[(size_t)p*COUT + c] = acc;
}

template<int C>
__global__ __launch_bounds__(256) void reduce_stats(const float* __restrict__ x, int n,
                                                    float* __restrict__ stats)
{
    constexpr int R = 256 / C;
    __shared__ float s1[256];
    __shared__ float s2[256];
    const int c = threadIdx.x % C;
    const int r = threadIdx.x / C;
    float a1 = 0.f, a2 = 0.f;
    for (int i = blockIdx.x * R + r; i < n; i += R * gridDim.x) {
        float v = x[(size_t)i*C + c];
        a1 += v;
        a2 += v * v;
    }
    s1[threadIdx.x] = a1;
    s2[threadIdx.x] = a2;
    __syncthreads();
    for (int off = 128; off >= C; off >>= 1) {
        if (threadIdx.x < off) {
            s1[threadIdx.x] += s1[threadIdx.x + off];
            s2[threadIdx.x] += s2[threadIdx.x + off];
        }
        __syncthreads();
    }
    if (threadIdx.x < C) {
        atomicAdd(&stats[c],     s1[threadIdx.x]);
        atomicAdd(&stats[C + c], s2[threadIdx.x]);
    }
}

template<int C>
__global__ __launch_bounds__(256) void bn_relu_apply(const float* __restrict__ x,
                                                     float* __restrict__ y, int n,
                                                     const float* __restrict__ stats,
                                                     const float* __restrict__ gamma,
                                                     const float* __restrict__ beta)
{
    const size_t i = (size_t)blockIdx.x * blockDim.x + threadIdx.x;
    if (i >= (size_t)n * C) return;
    const int c = (int)(i % C);
    const float inv_n = 1.f / (float)n;
    const float mu  = stats[c] * inv_n;
    const float var = stats[C + c] * inv_n - mu * mu;
    const float g = gamma[c] * rsqrtf(var + 1e-3f);
    const float v = (x[i] - mu) * g + beta[c];
    y[i] = v > 0.f ? v : 0.f;
}

extern "C" void kernel_launch(void* const* d_in, const int* in_sizes, int n_in,
                              void* d_out, int out_size, void* d_ws, size_t ws_size,
                              hipStream_t stream) {
    const float* vf    = (const float*)d_in[0];
    const float* w_in  = (const float*)d_in[1];
    const float* w1    = (const float*)d_in[2];
    const float* w2_0  = (const float*)d_in[3];
    const float* w2_1  = (const float*)d_in[4];
    const float* w2_2  = (const float*)d_in[5];
    const float* w3_0  = (const float*)d_in[6];
    const float* w3_1  = (const float*)d_in[7];
    const float* w3_2  = (const float*)d_in[8];
    const float* w4_0  = (const float*)d_in[9];
    const float* w4_1  = (const float*)d_in[10];
    const float* w4_2  = (const float*)d_in[11];
    const float* w_out = (const float*)d_in[12];
    const float* gamma = (const float*)d_in[13];
    const float* beta  = (const float*)d_in[14];
    const int* c1 = (const int*)d_in[15];
    const int* c2 = (const int*)d_in[16];
    const int* c3 = (const int*)d_in[17];
    const int* c4 = (const int*)d_in[18];
    const int* c5 = (const int*)d_in[19];
    const int N1 = in_sizes[15] / 4;
    const int N2 = in_sizes[16] / 4;
    const int N3 = in_sizes[17] / 4;
    const int N4 = in_sizes[18] / 4;
    const int N5 = in_sizes[19] / 4;

    // workspace layout
    const size_t G1 = (size_t)2*41*160*160;
    const size_t G2 = (size_t)2*21*80*80;
    const size_t G3 = (size_t)2*11*40*40;
    const size_t G4 = (size_t)2*5*20*20;
    int* grid1 = (int*)d_ws;
    int* grid2 = grid1 + G1;
    int* grid3 = grid2 + G2;
    int* grid4 = grid3 + G3;
    float* stats = (float*)(grid4 + G4);          // 12 layers x 256 floats
    float* bufA  = stats + 12*256;
    size_t maxE = (size_t)N1*16;
    if ((size_t)N2*32  > maxE) maxE = (size_t)N2*32;
    if ((size_t)N3*64  > maxE) maxE = (size_t)N3*64;
    if ((size_t)N4*64  > maxE) maxE = (size_t)N4*64;
    if ((size_t)N5*128 > maxE) maxE = (size_t)N5*128;
    maxE = (maxE + 3) & ~(size_t)3;
    float* bufB = bufA + maxE;

    hipMemsetAsync(grid1, 0xFF, (G1+G2+G3+G4)*sizeof(int), stream);
    hipMemsetAsync(stats, 0, 12*256*sizeof(float), stream);

    scatter_grid<<<(N1+255)/256, 256, 0, stream>>>(c1, N1, grid1, 41,160,160);
    scatter_grid<<<(N2+255)/256, 256, 0, stream>>>(c2, N2, grid2, 21, 80, 80);
    scatter_grid<<<(N3+255)/256, 256, 0, stream>>>(c3, N3, grid3, 11, 40, 40);
    scatter_grid<<<(N4+255)/256, 256, 0, stream>>>(c4, N4, grid4,  5, 20, 20);

#define LAYER(i, CIN, COUT, KD, KH, KW, FIN, GRD, OC, NP, WP, RAW, FOUT, D,H,W, SZ,SY,SX, PZ,PY,PX, GOFF) \
    { \
        constexpr int PTS_ = 256 / (COUT); \
        sp_conv<CIN,COUT,KD,KH,KW><<<((NP)+PTS_-1)/PTS_, 256, 0, stream>>>( \
            FIN, GRD, OC, NP, WP, RAW, D,H,W, SZ,SY,SX, PZ,PY,PX); \
        constexpr int R_ = 256 / (COUT); \
        int rb = ((NP) + R_ - 1) / R_; if (rb > 240) rb = 240; if (rb < 1) rb = 1; \
        reduce_stats<COUT><<<rb, 256, 0, stream>>>(RAW, NP, stats + (i)*256); \
        bn_relu_apply<COUT><<<((size_t)(NP)*(COUT) + 255)/256, 256, 0, stream>>>( \
            RAW, FOUT, NP, stats + (i)*256, gamma + (GOFF), beta + (GOFF)); \
    }

    LAYER( 0,  4, 16, 3,3,3, vf,   grid1, c1, N1, w_in,  bufA, bufA, 41,160,160, 1,1,1, 1,1,1,   0);
    LAYER( 1, 16, 16, 3,3,3, bufA, grid1, c1, N1, w1,    bufB, bufB, 41,160,160, 1,1,1, 1,1,1,  16);
    LAYER( 2, 16, 32, 3,3,3, bufB, grid1, c2, N2, w2_0,  bufA, bufA, 41,160,160, 2,2,2, 1,1,1,  32);
    LAYER( 3, 32, 32, 3,3,3, bufA, grid2, c2, N2, w2_1,  bufB, bufB, 21, 80, 80, 1,1,1, 1,1,1,  64);
    LAYER( 4, 32, 32, 3,3,3, bufB, grid2, c2, N2, w2_2,  bufA, bufA, 21, 80, 80, 1,1,1, 1,1,1,  96);
    LAYER( 5, 32, 64, 3,3,3, bufA, grid2, c3, N3, w3_0,  bufB, bufB, 21, 80, 80, 2,2,2, 1,1,1, 128);
    LAYER( 6, 64, 64, 3,3,3, bufB, grid3, c3, N3, w3_1,  bufA, bufA, 11, 40, 40, 1,1,1, 1,1,1, 192);
    LAYER( 7, 64, 64, 3,3,3, bufA, grid3, c3, N3, w3_2,  bufB, bufB, 11, 40, 40, 1,1,1, 1,1,1, 256);
    LAYER( 8, 64, 64, 3,3,3, bufB, grid3, c4, N4, w4_0,  bufA, bufA, 11, 40, 40, 2,2,2, 0,1,1, 320);
    LAYER( 9, 64, 64, 3,3,3, bufA, grid4, c4, N4, w4_1,  bufB, bufB,  5, 20, 20, 1,1,1, 1,1,1, 384);
    LAYER(10, 64, 64, 3,3,3, bufB, grid4, c4, N4, w4_2,  bufA, bufA,  5, 20, 20, 1,1,1, 1,1,1, 448);
    LAYER(11, 64,128, 3,1,1, bufA, grid4, c5, N5, w_out, bufB, (float*)d_out,
                                                                 5, 20, 20, 2,1,1, 0,0,0, 512);
#undef LAYER
}